// Round 1
// baseline (97.044 us; speedup 1.0000x reference)
//
#include <hip/hip_runtime.h>

// SRUCell: hy[b,h] = hx[b,h] + val[b] * ( sum_j W[h,j,idx[b]] * hx[b,j] + bias[h,idx[b]] )
// where idx[b] = argmax_i input[b,i] (input is one-hot), val[b] = input[b,idx[b]] (=1.0).
// Memory-bound: weight is 134 MB, read exactly once, coalesced via "lanes = batches"
// (for fixed (h,j) the 64 lanes gather within one aligned 128B line of 32 i-values).

constexpr int B  = 128;   // batch
constexpr int I  = 32;    // input size
constexpr int H  = 1024;  // hidden
constexpr int TH = 2;     // h-rows per block
constexpr int NC = 4;     // j-chunks per block (block = B*NC = 512 threads)
constexpr int CJ = H / NC;

__global__ void sru_idx_kernel(const float* __restrict__ inp,
                               int* __restrict__ idx, float* __restrict__ val) {
    int b = threadIdx.x;
    if (b >= B) return;
    float best = inp[b * I];
    int bi = 0;
#pragma unroll
    for (int i = 1; i < I; ++i) {
        float v = inp[b * I + i];
        if (v > best) { best = v; bi = i; }
    }
    idx[b] = bi;
    val[b] = best;
}

__global__ __launch_bounds__(B * NC) void sru_main_kernel(
    const float* __restrict__ hx, const float* __restrict__ w,
    const float* __restrict__ bias, const int* __restrict__ idx,
    const float* __restrict__ val, float* __restrict__ out) {
    const int t  = threadIdx.x;
    const int b  = t & (B - 1);   // lane dim = batch -> gather stays in one 128B line
    const int c  = t >> 7;        // j-chunk id
    const int h0 = blockIdx.x * TH;
    const int ib = idx[b];

    const float* hxp = hx + b * H + c * CJ;
    const float* wp  = w + (size_t)h0 * (H * I) + (size_t)(c * CJ) * I + ib;

    float acc[TH];
#pragma unroll
    for (int hh = 0; hh < TH; ++hh) acc[hh] = 0.f;

    for (int j = 0; j < CJ; j += 4) {
        const float4 x = *reinterpret_cast<const float4*>(hxp + j);
        const float xv[4] = {x.x, x.y, x.z, x.w};
#pragma unroll
        for (int hh = 0; hh < TH; ++hh) {
            const float* p = wp + (size_t)hh * (H * I) + (size_t)j * I;
#pragma unroll
            for (int jj = 0; jj < 4; ++jj)
                acc[hh] += xv[jj] * p[jj * I];
        }
    }

    // cross-chunk reduction in LDS
    __shared__ float red[NC][B][TH];  // 4 KB
#pragma unroll
    for (int hh = 0; hh < TH; ++hh) red[c][b][hh] = acc[hh];
    __syncthreads();

    if (c == 0) {
        const float v = val[b];
#pragma unroll
        for (int hh = 0; hh < TH; ++hh) {
            float r = 0.f;
#pragma unroll
            for (int cc = 0; cc < NC; ++cc) r += red[cc][b][hh];
            const int h = h0 + hh;
            out[b * H + h] = hx[b * H + h] + v * (r + bias[h * I + ib]);
        }
    }
}

extern "C" void kernel_launch(void* const* d_in, const int* in_sizes, int n_in,
                              void* d_out, int out_size, void* d_ws, size_t ws_size,
                              hipStream_t stream) {
    const float* inp    = (const float*)d_in[0];
    const float* state  = (const float*)d_in[1];  // [1,B,H] -> hx
    const float* weight = (const float*)d_in[2];  // [H,H,I]
    const float* bias   = (const float*)d_in[3];  // [H,I]
    float* out = (float*)d_out;

    int*   idx = (int*)d_ws;
    float* val = (float*)((char*)d_ws + B * sizeof(int));

    sru_idx_kernel<<<1, B, 0, stream>>>(inp, idx, val);
    sru_main_kernel<<<H / TH, B * NC, 0, stream>>>(state, weight, bias, idx, val, out);
}

// Round 2
// 83.771 us; speedup vs baseline: 1.1585x; 1.1585x over previous
//
#include <hip/hip_runtime.h>

// SRUCell as dense-streamed GEMM:
//   hy[b,h] = hx[b,h] + val[b]*bias[h,idx[b]] + C[h,b],
//   C[h,b]  = sum_k W2[h,k] * X[k,b],  k=(j,i) in W's native layout,
//   X[(j,i),b] = (i==idx[b]) ? val[b]*hx[b,j] : 0   (built in LDS, cheap)
// Weight (134 MB) is read exactly once, fully coalesced float4 streams; bf16
// MFMA (8.6 GF -> ~3.5us) hides under the memory stream. Split-K=32 with fp32
// atomicAdd epilogue onto an out buffer pre-initialized with hx + bias term.

constexpr int B  = 128;
constexpr int I  = 32;
constexpr int H  = 1024;
constexpr int K  = H * I;        // 32768
constexpr int BM = 128;
constexpr int BK = 64;
constexpr int SPLIT = 32;
constexpr int KC = K / SPLIT;    // 1024 k per block
constexpr int NT = KC / BK;      // 16 tiles

typedef short  short8 __attribute__((ext_vector_type(8)));
typedef float  f32x4  __attribute__((ext_vector_type(4)));

__device__ __forceinline__ unsigned short f2bf(float f) {
    unsigned u = __builtin_bit_cast(unsigned, f);
    return (unsigned short)((u + 0x7FFFu + ((u >> 16) & 1u)) >> 16);
}

__global__ void sru_idx_kernel(const float* __restrict__ inp,
                               int* __restrict__ idx, float* __restrict__ val) {
    int b = threadIdx.x;
    if (b >= B) return;
    float best = inp[b * I];
    int bi = 0;
#pragma unroll
    for (int i = 1; i < I; ++i) {
        float v = inp[b * I + i];
        if (v > best) { best = v; bi = i; }
    }
    idx[b] = bi;
    val[b] = best;
}

__global__ __launch_bounds__(256) void sru_init_kernel(
    const float* __restrict__ hx, const float* __restrict__ bias,
    const int* __restrict__ idx, const float* __restrict__ val,
    float* __restrict__ out) {
    int e = blockIdx.x * 256 + threadIdx.x;
    int b = e >> 10, h = e & (H - 1);
    out[e] = hx[e] + val[b] * bias[h * I + idx[b]];
}

__global__ __launch_bounds__(512, 1) void sru_gemm_kernel(
    const float* __restrict__ hx, const float* __restrict__ w,
    const int* __restrict__ idx, const float* __restrict__ val,
    float* __restrict__ out) {
    __shared__ __align__(16) unsigned short As[BM * BK];   // [m][kl], XOR-swizzled granules
    __shared__ __align__(16) unsigned short Xs[B * BK];    // [b][kl], XOR-swizzled
    __shared__ __align__(16) unsigned short hxs[B * 32];   // bf16(val[b]*hx[b, j-slice])

    const int tid = threadIdx.x;
    const int h0  = blockIdx.x * BM;
    const int kc0 = blockIdx.y * KC;

    // ---- stage hx slice [128 b][32 j], scaled by val[b] ----
    {
        int b  = tid >> 2;
        int c0 = (tid & 3) * 8;
        const float* p = hx + b * H + blockIdx.y * 32 + c0;
        float4 v0 = *reinterpret_cast<const float4*>(p);
        float4 v1 = *reinterpret_cast<const float4*>(p + 4);
        float vb = val[b];
        short8 s;
        s[0] = (short)f2bf(v0.x * vb); s[1] = (short)f2bf(v0.y * vb);
        s[2] = (short)f2bf(v0.z * vb); s[3] = (short)f2bf(v0.w * vb);
        s[4] = (short)f2bf(v1.x * vb); s[5] = (short)f2bf(v1.y * vb);
        s[6] = (short)f2bf(v1.z * vb); s[7] = (short)f2bf(v1.w * vb);
        *reinterpret_cast<short8*>(&hxs[b * 32 + c0]) = s;
    }

    // ---- staging geometry: each thread owns 16 consecutive k of one row ----
    const int arow = tid >> 2;                 // A row (m) / X row (b)
    const int akq  = (tid & 3) * 16;           // k offset in tile
    const float* ap = w + (size_t)(h0 + arow) * K + kc0 + akq;
    const int ag0 = ((akq >> 3) + 0) ^ (arow & 7);
    const int ag1 = ((akq >> 3) + 1) ^ (arow & 7);

    const int xb  = arow;
    const int ib  = idx[xb];
    const int i0  = akq & 31;
    const int jadd = akq >> 5;                 // 0 or 1
    const int xg0 = ag0, xg1 = ag1;            // same formula (xb==arow)

    // ---- wave/fragment geometry (8 waves: 2 on M x 4 on N) ----
    const int lane = tid & 63;
    const int wid  = tid >> 6;
    const int wm = wid & 1;
    const int wn = wid >> 1;
    const int kg = lane >> 4;
    int aoff[4][2], boff[2][2];
#pragma unroll
    for (int fm = 0; fm < 4; ++fm) {
        int r = wm * 64 + fm * 16 + (lane & 15);
#pragma unroll
        for (int ks = 0; ks < 2; ++ks)
            aoff[fm][ks] = r * 64 + ((ks * 4 + kg) ^ (r & 7)) * 8;
    }
#pragma unroll
    for (int fn = 0; fn < 2; ++fn) {
        int r = wn * 32 + fn * 16 + (lane & 15);
#pragma unroll
        for (int ks = 0; ks < 2; ++ks)
            boff[fn][ks] = r * 64 + ((ks * 4 + kg) ^ (r & 7)) * 8;
    }

    f32x4 acc[4][2];
#pragma unroll
    for (int fm = 0; fm < 4; ++fm)
#pragma unroll
        for (int fn = 0; fn < 2; ++fn)
            acc[fm][fn] = f32x4{0.f, 0.f, 0.f, 0.f};

    auto writeA = [&](float4 a0, float4 a1, float4 a2, float4 a3) {
        short8 s0, s1;
        s0[0] = (short)f2bf(a0.x); s0[1] = (short)f2bf(a0.y);
        s0[2] = (short)f2bf(a0.z); s0[3] = (short)f2bf(a0.w);
        s0[4] = (short)f2bf(a1.x); s0[5] = (short)f2bf(a1.y);
        s0[6] = (short)f2bf(a1.z); s0[7] = (short)f2bf(a1.w);
        s1[0] = (short)f2bf(a2.x); s1[1] = (short)f2bf(a2.y);
        s1[2] = (short)f2bf(a2.z); s1[3] = (short)f2bf(a2.w);
        s1[4] = (short)f2bf(a3.x); s1[5] = (short)f2bf(a3.y);
        s1[6] = (short)f2bf(a3.z); s1[7] = (short)f2bf(a3.w);
        *reinterpret_cast<short8*>(&As[arow * 64 + ag0 * 8]) = s0;
        *reinterpret_cast<short8*>(&As[arow * 64 + ag1 * 8]) = s1;
    };
    auto writeX = [&](int t) {
        int jloc = t * 2 + jadd;
        short hv = (short)hxs[xb * 32 + jloc];
        short8 x0, x1;
#pragma unroll
        for (int e = 0; e < 8; ++e) {
            x0[e] = (i0 + e == ib) ? hv : (short)0;
            x1[e] = (i0 + 8 + e == ib) ? hv : (short)0;
        }
        *reinterpret_cast<short8*>(&Xs[xb * 64 + xg0 * 8]) = x0;
        *reinterpret_cast<short8*>(&Xs[xb * 64 + xg1 * 8]) = x1;
    };
    auto compute = [&]() {
#pragma unroll
        for (int ks = 0; ks < 2; ++ks) {
            short8 af[4], bfr[2];
#pragma unroll
            for (int fm = 0; fm < 4; ++fm)
                af[fm] = *reinterpret_cast<const short8*>(&As[aoff[fm][ks]]);
#pragma unroll
            for (int fn = 0; fn < 2; ++fn)
                bfr[fn] = *reinterpret_cast<const short8*>(&Xs[boff[fn][ks]]);
#pragma unroll
            for (int fm = 0; fm < 4; ++fm)
#pragma unroll
                for (int fn = 0; fn < 2; ++fn)
                    acc[fm][fn] = __builtin_amdgcn_mfma_f32_16x16x32_bf16(
                        af[fm], bfr[fn], acc[fm][fn], 0, 0, 0);
        }
    };

    // ---- prologue: tile 0 (loads issued before the hx barrier) ----
    float4 r0 = *reinterpret_cast<const float4*>(ap + 0);
    float4 r1 = *reinterpret_cast<const float4*>(ap + 4);
    float4 r2 = *reinterpret_cast<const float4*>(ap + 8);
    float4 r3 = *reinterpret_cast<const float4*>(ap + 12);
    __syncthreads();               // hxs visible
    writeX(0);
    writeA(r0, r1, r2, r3);
    __syncthreads();               // tile 0 ready

    for (int t = 0; t < NT; ++t) {
        if (t + 1 < NT) {          // T14: issue next tile's global loads early
            const float* p = ap + (t + 1) * BK;
            r0 = *reinterpret_cast<const float4*>(p + 0);
            r1 = *reinterpret_cast<const float4*>(p + 4);
            r2 = *reinterpret_cast<const float4*>(p + 8);
            r3 = *reinterpret_cast<const float4*>(p + 12);
        }
        compute();
        __syncthreads();           // all waves done reading LDS
        if (t + 1 < NT) {
            writeA(r0, r1, r2, r3);
            writeX(t + 1);
        }
        __syncthreads();           // next tile ready
    }

    // ---- epilogue: split-K partials -> fp32 atomics ----
#pragma unroll
    for (int fm = 0; fm < 4; ++fm) {
#pragma unroll
        for (int fn = 0; fn < 2; ++fn) {
            int n  = wn * 32 + fn * 16 + (lane & 15);      // batch
            int m0 = wm * 64 + fm * 16 + (lane >> 4) * 4;  // h within block
#pragma unroll
            for (int rr = 0; rr < 4; ++rr)
                atomicAdd(&out[(size_t)n * H + h0 + m0 + rr], acc[fm][fn][rr]);
        }
    }
}

extern "C" void kernel_launch(void* const* d_in, const int* in_sizes, int n_in,
                              void* d_out, int out_size, void* d_ws, size_t ws_size,
                              hipStream_t stream) {
    const float* inp    = (const float*)d_in[0];
    const float* state  = (const float*)d_in[1];  // [1,B,H]
    const float* weight = (const float*)d_in[2];  // [H,H,I]
    const float* bias   = (const float*)d_in[3];  // [H,I]
    float* out = (float*)d_out;

    int*   idx = (int*)d_ws;
    float* val = (float*)((char*)d_ws + B * sizeof(int));

    sru_idx_kernel<<<1, B, 0, stream>>>(inp, idx, val);
    sru_init_kernel<<<(B * H) / 256, 256, 0, stream>>>(state, bias, idx, val, out);
    sru_gemm_kernel<<<dim3(H / BM, SPLIT), 512, 0, stream>>>(state, weight, idx, val, out);
}

// Round 4
// 41.981 us; speedup vs baseline: 2.3116x; 1.9954x over previous
//
#include <hip/hip_runtime.h>

// SRUCell as dense-streamed GEMM:
//   hy[b,h] = hx[b,h] + val[b]*bias[h,idx[b]] + C[h,b],
//   C[h,b]  = sum_k W2[h,k] * X[k,b],  k=(j,i) in W's native layout,
//   X[(j,i),b] = (i==idx[b]) ? val[b]*hx[b,j] : 0   (built in LDS, cheap)
// Weight (134 MB) read exactly once, coalesced float4 streams; bf16 MFMA
// (8.6 GF) hides under the stream. Split-K=32 partials -> workspace (plain
// float4 stores, NO atomics) -> reduce kernel. Round-2 atomics caused 64 MB
// of HBM writes + TCC serialization (~90us tail); this removes them.

constexpr int B  = 128;
constexpr int I  = 32;
constexpr int H  = 1024;
constexpr int K  = H * I;        // 32768
constexpr int BM = 128;
constexpr int BK = 64;
constexpr int SPLIT = 32;
constexpr int KC = K / SPLIT;    // 1024 k per block
constexpr int NT = KC / BK;      // 16 tiles

typedef short  short8 __attribute__((ext_vector_type(8)));
typedef float  f32x4  __attribute__((ext_vector_type(4)));

__device__ __forceinline__ unsigned short f2bf(float f) {
    unsigned u = __builtin_bit_cast(unsigned, f);
    return (unsigned short)((u + 0x7FFFu + ((u >> 16) & 1u)) >> 16);
}

__global__ void sru_idx_kernel(const float* __restrict__ inp,
                               int* __restrict__ idx, float* __restrict__ val) {
    int b = threadIdx.x;
    if (b >= B) return;
    float best = inp[b * I];
    int bi = 0;
#pragma unroll
    for (int i = 1; i < I; ++i) {
        float v = inp[b * I + i];
        if (v > best) { best = v; bi = i; }
    }
    idx[b] = bi;
    val[b] = best;
}

// Fallback-path init (atomic epilogue needs out pre-initialized).
__global__ __launch_bounds__(256) void sru_init_kernel(
    const float* __restrict__ hx, const float* __restrict__ bias,
    const int* __restrict__ idx, const float* __restrict__ val,
    float* __restrict__ out) {
    int e = blockIdx.x * 256 + threadIdx.x;
    int b = e >> 10, h = e & (H - 1);
    out[e] = hx[e] + val[b] * bias[h * I + idx[b]];
}

// out[b,h] = hx[b,h] + val[b]*bias[h,idx[b]] + sum_s partial[s][b][h]
__global__ __launch_bounds__(256) void sru_reduce_kernel(
    const float* __restrict__ hx, const float* __restrict__ bias,
    const int* __restrict__ idx, const float* __restrict__ val,
    const float* __restrict__ partial, float* __restrict__ out) {
    int e  = blockIdx.x * 256 + threadIdx.x;   // indexes float4 over B*H/4
    int b  = e >> 8;                           // H/4 = 256 float4 per row
    int h4 = (e & 255) * 4;
    float4 s = *reinterpret_cast<const float4*>(&hx[b * H + h4]);
    int ib = idx[b];
    float v = val[b];
    s.x += v * bias[(h4 + 0) * I + ib];
    s.y += v * bias[(h4 + 1) * I + ib];
    s.z += v * bias[(h4 + 2) * I + ib];
    s.w += v * bias[(h4 + 3) * I + ib];
#pragma unroll
    for (int sp = 0; sp < SPLIT; ++sp) {
        float4 p = *reinterpret_cast<const float4*>(
            &partial[((size_t)sp * B + b) * H + h4]);
        s.x += p.x; s.y += p.y; s.z += p.z; s.w += p.w;
    }
    *reinterpret_cast<float4*>(&out[b * H + h4]) = s;
}

template <bool USE_WS>
__global__ __launch_bounds__(512, 1) void sru_gemm_kernel(
    const float* __restrict__ hx, const float* __restrict__ w,
    const int* __restrict__ idx, const float* __restrict__ val,
    float* __restrict__ out) {
    __shared__ __align__(16) unsigned short As[BM * BK];   // XOR-swizzled granules
    __shared__ __align__(16) unsigned short Xs[B * BK];
    __shared__ __align__(16) unsigned short hxs[B * 32];   // bf16(val[b]*hx[b, j-slice])

    const int tid = threadIdx.x;
    const int h0  = blockIdx.x * BM;
    const int kc0 = blockIdx.y * KC;

    // ---- stage hx slice [128 b][32 j], scaled by val[b] ----
    {
        int b  = tid >> 2;
        int c0 = (tid & 3) * 8;
        const float* p = hx + b * H + blockIdx.y * 32 + c0;
        float4 v0 = *reinterpret_cast<const float4*>(p);
        float4 v1 = *reinterpret_cast<const float4*>(p + 4);
        float vb = val[b];
        short8 s;
        s[0] = (short)f2bf(v0.x * vb); s[1] = (short)f2bf(v0.y * vb);
        s[2] = (short)f2bf(v0.z * vb); s[3] = (short)f2bf(v0.w * vb);
        s[4] = (short)f2bf(v1.x * vb); s[5] = (short)f2bf(v1.y * vb);
        s[6] = (short)f2bf(v1.z * vb); s[7] = (short)f2bf(v1.w * vb);
        *reinterpret_cast<short8*>(&hxs[b * 32 + c0]) = s;
    }

    // ---- staging geometry: each thread owns 16 consecutive k of one row ----
    const int arow = tid >> 2;                 // A row (m) / X row (b)
    const int akq  = (tid & 3) * 16;           // k offset in tile
    const float* ap = w + (size_t)(h0 + arow) * K + kc0 + akq;
    const int ag0 = ((akq >> 3) + 0) ^ (arow & 7);
    const int ag1 = ((akq >> 3) + 1) ^ (arow & 7);

    const int xb  = arow;
    const int ib  = idx[xb];
    const int i0  = akq & 31;
    const int jadd = akq >> 5;                 // 0 or 1
    const int xg0 = ag0, xg1 = ag1;

    // ---- wave/fragment geometry (8 waves: 2 on M x 4 on N) ----
    const int lane = tid & 63;
    const int wid  = tid >> 6;
    const int wm = wid & 1;
    const int wn = wid >> 1;
    const int kg = lane >> 4;
    int aoff[4][2], boff[2][2];
#pragma unroll
    for (int fm = 0; fm < 4; ++fm) {
        int r = wm * 64 + fm * 16 + (lane & 15);
#pragma unroll
        for (int ks = 0; ks < 2; ++ks)
            aoff[fm][ks] = r * 64 + ((ks * 4 + kg) ^ (r & 7)) * 8;
    }
#pragma unroll
    for (int fn = 0; fn < 2; ++fn) {
        int r = wn * 32 + fn * 16 + (lane & 15);
#pragma unroll
        for (int ks = 0; ks < 2; ++ks)
            boff[fn][ks] = r * 64 + ((ks * 4 + kg) ^ (r & 7)) * 8;
    }

    f32x4 acc[4][2];
#pragma unroll
    for (int fm = 0; fm < 4; ++fm)
#pragma unroll
        for (int fn = 0; fn < 2; ++fn)
            acc[fm][fn] = f32x4{0.f, 0.f, 0.f, 0.f};

    auto writeA = [&](float4 a0, float4 a1, float4 a2, float4 a3) {
        short8 s0, s1;
        s0[0] = (short)f2bf(a0.x); s0[1] = (short)f2bf(a0.y);
        s0[2] = (short)f2bf(a0.z); s0[3] = (short)f2bf(a0.w);
        s0[4] = (short)f2bf(a1.x); s0[5] = (short)f2bf(a1.y);
        s0[6] = (short)f2bf(a1.z); s0[7] = (short)f2bf(a1.w);
        s1[0] = (short)f2bf(a2.x); s1[1] = (short)f2bf(a2.y);
        s1[2] = (short)f2bf(a2.z); s1[3] = (short)f2bf(a2.w);
        s1[4] = (short)f2bf(a3.x); s1[5] = (short)f2bf(a3.y);
        s1[6] = (short)f2bf(a3.z); s1[7] = (short)f2bf(a3.w);
        *reinterpret_cast<short8*>(&As[arow * 64 + ag0 * 8]) = s0;
        *reinterpret_cast<short8*>(&As[arow * 64 + ag1 * 8]) = s1;
    };
    auto writeX = [&](int t) {
        int jloc = t * 2 + jadd;
        short hv = (short)hxs[xb * 32 + jloc];
        short8 x0, x1;
#pragma unroll
        for (int e = 0; e < 8; ++e) {
            x0[e] = (i0 + e == ib) ? hv : (short)0;
            x1[e] = (i0 + 8 + e == ib) ? hv : (short)0;
        }
        *reinterpret_cast<short8*>(&Xs[xb * 64 + xg0 * 8]) = x0;
        *reinterpret_cast<short8*>(&Xs[xb * 64 + xg1 * 8]) = x1;
    };
    auto compute = [&]() {
#pragma unroll
        for (int ks = 0; ks < 2; ++ks) {
            short8 af[4], bfr[2];
#pragma unroll
            for (int fm = 0; fm < 4; ++fm)
                af[fm] = *reinterpret_cast<const short8*>(&As[aoff[fm][ks]]);
#pragma unroll
            for (int fn = 0; fn < 2; ++fn)
                bfr[fn] = *reinterpret_cast<const short8*>(&Xs[boff[fn][ks]]);
#pragma unroll
            for (int fm = 0; fm < 4; ++fm)
#pragma unroll
                for (int fn = 0; fn < 2; ++fn)
                    acc[fm][fn] = __builtin_amdgcn_mfma_f32_16x16x32_bf16(
                        af[fm], bfr[fn], acc[fm][fn], 0, 0, 0);
        }
    };

    // ---- prologue: tile 0 ----
    float4 r0 = *reinterpret_cast<const float4*>(ap + 0);
    float4 r1 = *reinterpret_cast<const float4*>(ap + 4);
    float4 r2 = *reinterpret_cast<const float4*>(ap + 8);
    float4 r3 = *reinterpret_cast<const float4*>(ap + 12);
    __syncthreads();               // hxs visible
    writeX(0);
    writeA(r0, r1, r2, r3);
    __syncthreads();               // tile 0 ready

    for (int t = 0; t < NT; ++t) {
        if (t + 1 < NT) {          // issue next tile's global loads early
            const float* p = ap + (t + 1) * BK;
            r0 = *reinterpret_cast<const float4*>(p + 0);
            r1 = *reinterpret_cast<const float4*>(p + 4);
            r2 = *reinterpret_cast<const float4*>(p + 8);
            r3 = *reinterpret_cast<const float4*>(p + 12);
        }
        compute();
        __syncthreads();
        if (t + 1 < NT) {
            writeA(r0, r1, r2, r3);
            writeX(t + 1);
        }
        __syncthreads();
    }

    // ---- epilogue ----
    if constexpr (USE_WS) {
        // plain coalescing-friendly float4 stores to partial[split][b][h]
        float* pp = out + (size_t)blockIdx.y * B * H;  // 'out' = partial base
#pragma unroll
        for (int fm = 0; fm < 4; ++fm) {
#pragma unroll
            for (int fn = 0; fn < 2; ++fn) {
                int n  = wn * 32 + fn * 16 + (lane & 15);      // batch
                int m0 = wm * 64 + fm * 16 + (lane >> 4) * 4;  // h within block
                float4 vv = {acc[fm][fn][0], acc[fm][fn][1],
                             acc[fm][fn][2], acc[fm][fn][3]};
                *reinterpret_cast<float4*>(&pp[(size_t)n * H + h0 + m0]) = vv;
            }
        }
    } else {
#pragma unroll
        for (int fm = 0; fm < 4; ++fm) {
#pragma unroll
            for (int fn = 0; fn < 2; ++fn) {
                int n  = wn * 32 + fn * 16 + (lane & 15);
                int m0 = wm * 64 + fm * 16 + (lane >> 4) * 4;
#pragma unroll
                for (int rr = 0; rr < 4; ++rr)
                    atomicAdd(&out[(size_t)n * H + h0 + m0 + rr], acc[fm][fn][rr]);
            }
        }
    }
}

extern "C" void kernel_launch(void* const* d_in, const int* in_sizes, int n_in,
                              void* d_out, int out_size, void* d_ws, size_t ws_size,
                              hipStream_t stream) {
    const float* inp    = (const float*)d_in[0];
    const float* state  = (const float*)d_in[1];  // [1,B,H]
    const float* weight = (const float*)d_in[2];  // [H,H,I]
    const float* bias   = (const float*)d_in[3];  // [H,I]
    float* out = (float*)d_out;

    int*   idx = (int*)d_ws;
    float* val = (float*)((char*)d_ws + B * sizeof(int));
    float* partial = (float*)((char*)d_ws + 1024);   // 16B-aligned
    const size_t need = 1024 + (size_t)SPLIT * B * H * sizeof(float);

    sru_idx_kernel<<<1, B, 0, stream>>>(inp, idx, val);

    if (ws_size >= need) {
        sru_gemm_kernel<true><<<dim3(H / BM, SPLIT), 512, 0, stream>>>(
            state, weight, idx, val, partial);
        sru_reduce_kernel<<<(B * H / 4) / 256, 256, 0, stream>>>(
            state, bias, idx, val, partial, out);
    } else {
        sru_init_kernel<<<(B * H) / 256, 256, 0, stream>>>(state, bias, idx, val, out);
        sru_gemm_kernel<false><<<dim3(H / BM, SPLIT), 512, 0, stream>>>(
            state, weight, idx, val, out);
    }
}

// Round 7
// 35.281 us; speedup vs baseline: 2.7506x; 1.1899x over previous
//
#include <hip/hip_runtime.h>

// SRUCell as dense-streamed GEMM, v3:
//   hy[b,h] = hx[b,h] + val[b]*bias[h,idx[b]] + sum_k W2[h,k]*X[k,b]
//   k=(j,i) native W layout; X[(j,i),b] = (i==idx[b]) ? val[b]*hx[b,j] : 0.
// Changes vs round 4 (42us): idx argmax folded into consumers (one fewer
// serialized launch); X built IN REGISTERS via per-lane one-hot bit-mask
// (kills Xs LDS + its bank conflicts); BM 128->64 => grid 512 = 2 blocks/CU;
// As double-buffered with ONE barrier per tile.

constexpr int B  = 128;
constexpr int I  = 32;
constexpr int H  = 1024;
constexpr int K  = H * I;        // 32768
constexpr int BM = 64;
constexpr int BK = 64;
constexpr int SPLIT = 32;
constexpr int KC = K / SPLIT;    // 1024 (32 j per split)
constexpr int NT = KC / BK;      // 16 tiles

typedef short  short8 __attribute__((ext_vector_type(8)));
typedef unsigned int uint4v __attribute__((ext_vector_type(4)));
typedef float  f32x4  __attribute__((ext_vector_type(4)));

__device__ __forceinline__ unsigned short f2bf(float f) {
    unsigned u = __builtin_bit_cast(unsigned, f);
    return (unsigned short)((u + 0x7FFFu + ((u >> 16) & 1u)) >> 16);
}

__device__ __forceinline__ void argmax32(const float* __restrict__ inp, int b,
                                         int& ib, float& vb) {
    float best = inp[b * I];
    int bi = 0;
#pragma unroll
    for (int i = 1; i < I; ++i) {
        float v = inp[b * I + i];
        if (v > best) { best = v; bi = i; }
    }
    ib = bi; vb = best;
}

// Fallback-path init (atomic epilogue needs out pre-initialized).
__global__ __launch_bounds__(256) void sru_init_kernel(
    const float* __restrict__ inp, const float* __restrict__ hx,
    const float* __restrict__ bias, float* __restrict__ out) {
    int e = blockIdx.x * 256 + threadIdx.x;
    int b = e >> 10, h = e & (H - 1);
    int ib; float v; argmax32(inp, b, ib, v);
    out[e] = hx[e] + v * bias[h * I + ib];
}

// out[b,h] = hx[b,h] + val[b]*bias[h,idx[b]] + sum_s partial[s][b][h]
__global__ __launch_bounds__(256) void sru_reduce_kernel(
    const float* __restrict__ inp, const float* __restrict__ hx,
    const float* __restrict__ bias, const float* __restrict__ partial,
    float* __restrict__ out) {
    const int b  = blockIdx.x;            // grid = B
    const int h4 = threadIdx.x * 4;       // 256 threads x 4 h = H
    int ib; float v; argmax32(inp, b, ib, v);   // broadcast loads, cheap
    float4 s = *reinterpret_cast<const float4*>(&hx[b * H + h4]);
    s.x += v * bias[(h4 + 0) * I + ib];
    s.y += v * bias[(h4 + 1) * I + ib];
    s.z += v * bias[(h4 + 2) * I + ib];
    s.w += v * bias[(h4 + 3) * I + ib];
#pragma unroll
    for (int sp = 0; sp < SPLIT; ++sp) {
        float4 p = *reinterpret_cast<const float4*>(
            &partial[((size_t)sp * B + b) * H + h4]);
        s.x += p.x; s.y += p.y; s.z += p.z; s.w += p.w;
    }
    *reinterpret_cast<float4*>(&out[b * H + h4]) = s;
}

template <bool USE_WS>
__global__ __launch_bounds__(512, 4) void sru_gemm_kernel(
    const float* __restrict__ inp, const float* __restrict__ hx,
    const float* __restrict__ w, float* __restrict__ out) {
    __shared__ __align__(16) unsigned short As[2][BM * BK];  // 2 x 8 KB, XOR-swizzled
    __shared__ __align__(16) unsigned short hxs[B * 32];     // bf16(val[b]*hx[b,j-slice])
    __shared__ int   idxs[B];
    __shared__ float vals[B];

    const int tid = threadIdx.x;
    const int h0  = blockIdx.x * BM;
    const int by  = blockIdx.y;
    const int kc0 = by * KC;

    // ---- per-block idx/val (one-hot argmax), replaces separate kernel ----
    if (tid < B) {
        int ib; float vb; argmax32(inp, tid, ib, vb);
        idxs[tid] = ib; vals[tid] = vb;
    }
    __syncthreads();

    // ---- stage hx slice [128 b][32 j], scaled by val[b] ----
    {
        int b  = tid >> 2;
        int c0 = (tid & 3) * 8;
        const float* p = hx + b * H + by * 32 + c0;
        float4 v0 = *reinterpret_cast<const float4*>(p);
        float4 v1 = *reinterpret_cast<const float4*>(p + 4);
        float vb = vals[b];
        short8 s;
        s[0] = (short)f2bf(v0.x * vb); s[1] = (short)f2bf(v0.y * vb);
        s[2] = (short)f2bf(v0.z * vb); s[3] = (short)f2bf(v0.w * vb);
        s[4] = (short)f2bf(v1.x * vb); s[5] = (short)f2bf(v1.y * vb);
        s[6] = (short)f2bf(v1.z * vb); s[7] = (short)f2bf(v1.w * vb);
        *reinterpret_cast<short8*>(&hxs[b * 32 + c0]) = s;
    }

    // ---- A staging: 64 rows x 8 threads/row, 8 floats (1 granule) each ----
    const int arow = tid >> 3;
    const int ag   = tid & 7;
    const float* ap = w + (size_t)(h0 + arow) * K + kc0 + ag * 8;
    const int awoff = arow * 64 + (ag ^ (arow & 7)) * 8;

    float4 r0, r1;
    auto loadA = [&](int t) {
        const float* p = ap + t * BK;
        r0 = *reinterpret_cast<const float4*>(p);
        r1 = *reinterpret_cast<const float4*>(p + 4);
    };
    auto writeA = [&](int buf) {
        short8 s;
        s[0] = (short)f2bf(r0.x); s[1] = (short)f2bf(r0.y);
        s[2] = (short)f2bf(r0.z); s[3] = (short)f2bf(r0.w);
        s[4] = (short)f2bf(r1.x); s[5] = (short)f2bf(r1.y);
        s[6] = (short)f2bf(r1.z); s[7] = (short)f2bf(r1.w);
        *reinterpret_cast<short8*>(&As[buf][awoff]) = s;
    };

    // ---- wave geometry: 8 waves = 2(M) x 4(N) ----
    const int lane = tid & 63;
    const int wid  = tid >> 6;
    const int wm = wid & 1;
    const int wn = wid >> 1;
    const int kg = lane >> 4;          // k-octet owned by this lane

    int aoff[2][2];
#pragma unroll
    for (int fm = 0; fm < 2; ++fm) {
        int r = wm * 32 + fm * 16 + (lane & 15);
#pragma unroll
        for (int ks = 0; ks < 2; ++ks)
            aoff[fm][ks] = r * 64 + (((ks * 4 + kg) ^ (r & 7))) * 8;
    }

    // ---- per-lane one-hot B-frag masks (X built in registers) ----
    int bcol[2];
    uint4v msk[2];
#pragma unroll
    for (int fn = 0; fn < 2; ++fn) {
        bcol[fn] = wn * 32 + fn * 16 + (lane & 15);
        int rel = idxs[bcol[fn]] - kg * 8;   // hot position within this lane's octet
        uint4v m;
#pragma unroll
        for (int q = 0; q < 4; ++q) {
            unsigned lo = (rel == 2 * q)     ? 0xFFFFu : 0u;
            unsigned hi = (rel == 2 * q + 1) ? 0xFFFFu : 0u;
            m[q] = lo | (hi << 16);
        }
        msk[fn] = m;
    }

    f32x4 acc[2][2];
#pragma unroll
    for (int fm = 0; fm < 2; ++fm)
#pragma unroll
        for (int fn = 0; fn < 2; ++fn)
            acc[fm][fn] = f32x4{0.f, 0.f, 0.f, 0.f};

    auto compute = [&](int buf, int t) {
#pragma unroll
        for (int ks = 0; ks < 2; ++ks) {
            short8 af[2], xf[2];
#pragma unroll
            for (int fm = 0; fm < 2; ++fm)
                af[fm] = *reinterpret_cast<const short8*>(&As[buf][aoff[fm][ks]]);
#pragma unroll
            for (int fn = 0; fn < 2; ++fn) {
                unsigned hv = hxs[bcol[fn] * 32 + t * 2 + ks];  // j const per 32-k slice
                unsigned hv32 = hv | (hv << 16);
                uint4v xd;
#pragma unroll
                for (int q = 0; q < 4; ++q) xd[q] = msk[fn][q] & hv32;
                xf[fn] = __builtin_bit_cast(short8, xd);
            }
#pragma unroll
            for (int fm = 0; fm < 2; ++fm)
#pragma unroll
                for (int fn = 0; fn < 2; ++fn)
                    acc[fm][fn] = __builtin_amdgcn_mfma_f32_16x16x32_bf16(
                        af[fm], xf[fn], acc[fm][fn], 0, 0, 0);
        }
    };

    // ---- main loop: double-buffered As, ONE barrier per tile ----
    loadA(0);
    __syncthreads();          // hxs/idxs visible
    writeA(0);
    loadA(1);
    __syncthreads();          // As[0] ready
    int cur = 0;
    for (int t = 0; t < NT; ++t) {
        if (t + 1 < NT) {
            writeA(cur ^ 1);              // tile t+1 (regs)
            if (t + 2 < NT) loadA(t + 2); // prefetch next into regs
        }
        compute(cur, t);
        __syncthreads();                  // As[cur^1] ready, all done with As[cur]
        cur ^= 1;
    }

    // ---- epilogue ----
    if constexpr (USE_WS) {
        float* pp = out + (size_t)by * (B * H);   // 'out' = partial base
#pragma unroll
        for (int fm = 0; fm < 2; ++fm) {
#pragma unroll
            for (int fn = 0; fn < 2; ++fn) {
                int n  = bcol[fn];                          // batch
                int m0 = wm * 32 + fm * 16 + (lane >> 4) * 4;
                float4 vv = {acc[fm][fn][0], acc[fm][fn][1],
                             acc[fm][fn][2], acc[fm][fn][3]};
                *reinterpret_cast<float4*>(&pp[(size_t)n * H + h0 + m0]) = vv;
            }
        }
    } else {
#pragma unroll
        for (int fm = 0; fm < 2; ++fm) {
#pragma unroll
            for (int fn = 0; fn < 2; ++fn) {
                int n  = bcol[fn];
                int m0 = wm * 32 + fm * 16 + (lane >> 4) * 4;
#pragma unroll
                for (int rr = 0; rr < 4; ++rr)
                    atomicAdd(&out[(size_t)n * H + h0 + m0 + rr], acc[fm][fn][rr]);
            }
        }
    }
}

extern "C" void kernel_launch(void* const* d_in, const int* in_sizes, int n_in,
                              void* d_out, int out_size, void* d_ws, size_t ws_size,
                              hipStream_t stream) {
    const float* inp    = (const float*)d_in[0];
    const float* state  = (const float*)d_in[1];  // [1,B,H]
    const float* weight = (const float*)d_in[2];  // [H,H,I]
    const float* bias   = (const float*)d_in[3];  // [H,I]
    float* out = (float*)d_out;

    float* partial = (float*)d_ws;
    const size_t need = (size_t)SPLIT * B * H * sizeof(float);

    if (ws_size >= need) {
        sru_gemm_kernel<true><<<dim3(H / BM, SPLIT), 512, 0, stream>>>(
            inp, state, weight, partial);
        sru_reduce_kernel<<<B, 256, 0, stream>>>(
            inp, state, bias, partial, out);
    } else {
        sru_init_kernel<<<(B * H) / 256, 256, 0, stream>>>(inp, state, bias, out);
        sru_gemm_kernel<false><<<dim3(H / BM, SPLIT), 512, 0, stream>>>(
            inp, state, weight, out);
    }
}

// Round 8
// 34.575 us; speedup vs baseline: 2.8068x; 1.0204x over previous
//
#include <hip/hip_runtime.h>

// SRUCell as dense-streamed GEMM, v4 (barrier-free main loop):
//   hy[b,h] = hx[b,h] + val[b]*bias[h,idx[b]] + sum_{j,i} W[h,j,i]*X[(j,i),b]
//   X[(j,i),b] = (i==idx[b]) ? val[b]*hx[b,j] : 0  (one-hot input).
// Each wave owns 16 h-rows x 1024-k split; the MFMA A-fragment
// (lane -> A[l&15][(l>>4)*8+e], proven by the passing v3 kernel) is loaded
// DIRECTLY from global (16 rows x 128B contiguous per instruction), cvt to
// bf16 in-reg; B built in registers from per-lane one-hot masks + an 8KB
// [j][b] LDS table of bf16(val*hx). No LDS A-tile, ZERO barriers in the
// K-loop, depth-2 register pipeline (~32KB/CU in flight).

constexpr int B  = 128;
constexpr int I  = 32;
constexpr int H  = 1024;
constexpr int K  = H * I;      // 32768
constexpr int SPLIT = 32;
constexpr int JC = H / SPLIT;  // 32 j-values per split (= 1024 k)
constexpr int WPB = 4;         // waves per block (4 row-groups of 16 h)

typedef short  short8 __attribute__((ext_vector_type(8)));
typedef unsigned int uint4v __attribute__((ext_vector_type(4)));
typedef float  f32x4  __attribute__((ext_vector_type(4)));

__device__ __forceinline__ unsigned short f2bf(float f) {
    unsigned u = __builtin_bit_cast(unsigned, f);
    return (unsigned short)((u + 0x7FFFu + ((u >> 16) & 1u)) >> 16);
}

__device__ __forceinline__ void argmax32(const float* __restrict__ inp, int b,
                                         int& ib, float& vb) {
    float best = inp[b * I];
    int bi = 0;
#pragma unroll
    for (int i = 1; i < I; ++i) {
        float v = inp[b * I + i];
        if (v > best) { best = v; bi = i; }
    }
    ib = bi; vb = best;
}

// Fallback-path init (atomic epilogue needs out pre-initialized).
__global__ __launch_bounds__(256) void sru_init_kernel(
    const float* __restrict__ inp, const float* __restrict__ hx,
    const float* __restrict__ bias, float* __restrict__ out) {
    int e = blockIdx.x * 256 + threadIdx.x;
    int b = e >> 10, h = e & (H - 1);
    int ib; float v; argmax32(inp, b, ib, v);
    out[e] = hx[e] + v * bias[h * I + ib];
}

// out[b,h] = hx[b,h] + val[b]*bias[h,idx[b]] + sum_s partial[s][b][h]
// grid 256 blocks x 128 threads (all CUs busy).
__global__ __launch_bounds__(128) void sru_reduce_kernel(
    const float* __restrict__ inp, const float* __restrict__ hx,
    const float* __restrict__ bias, const float* __restrict__ partial,
    float* __restrict__ out) {
    const int b  = blockIdx.x >> 1;
    const int h4 = (blockIdx.x & 1) * 512 + threadIdx.x * 4;
    int ib; float v; argmax32(inp, b, ib, v);   // broadcast loads, cheap
    float4 s = *reinterpret_cast<const float4*>(&hx[b * H + h4]);
    s.x += v * bias[(h4 + 0) * I + ib];
    s.y += v * bias[(h4 + 1) * I + ib];
    s.z += v * bias[(h4 + 2) * I + ib];
    s.w += v * bias[(h4 + 3) * I + ib];
#pragma unroll
    for (int sp = 0; sp < SPLIT; ++sp) {
        float4 p = *reinterpret_cast<const float4*>(
            &partial[((size_t)sp * B + b) * H + h4]);
        s.x += p.x; s.y += p.y; s.z += p.z; s.w += p.w;
    }
    *reinterpret_cast<float4*>(&out[b * H + h4]) = s;
}

template <bool USE_WS>
__global__ __launch_bounds__(256, 2) void sru_gemm_kernel(
    const float* __restrict__ inp, const float* __restrict__ hx,
    const float* __restrict__ w, float* __restrict__ out) {
    __shared__ unsigned short hxs[JC * B];   // [j][b] bf16(val[b]*hx[b,j0+j]), 8KB
    __shared__ int   idxs[B];
    __shared__ float vals[B];

    const int tid  = threadIdx.x;
    const int lane = tid & 63;
    const int wid  = tid >> 6;
    const int by   = blockIdx.y;
    const int j0   = by * JC;
    const int h0   = blockIdx.x * (16 * WPB) + wid * 16;
    const int r16  = lane & 15;
    const int kg   = lane >> 4;

    // ---- per-block idx/val (one-hot argmax) ----
    if (tid < B) {
        int ib; float vb; argmax32(inp, tid, ib, vb);
        idxs[tid] = ib; vals[tid] = vb;
    }
    __syncthreads();

    // ---- stage hxs[j][b] = bf16(val[b] * hx[b][j0+j]) ----
    {
        int b  = tid >> 1;
        int jh = (tid & 1) * 16;
        const float* p = hx + b * H + j0 + jh;
        float vb = vals[b];
#pragma unroll
        for (int q = 0; q < 4; ++q) {
            float4 v = *reinterpret_cast<const float4*>(p + q * 4);
            hxs[(jh + q * 4 + 0) * B + b] = f2bf(v.x * vb);
            hxs[(jh + q * 4 + 1) * B + b] = f2bf(v.y * vb);
            hxs[(jh + q * 4 + 2) * B + b] = f2bf(v.z * vb);
            hxs[(jh + q * 4 + 3) * B + b] = f2bf(v.w * vb);
        }
    }
    __syncthreads();

    // ---- per-lane one-hot B-frag masks (8 batch groups of 16) ----
    uint4v msk[8];
#pragma unroll
    for (int g = 0; g < 8; ++g) {
        int rel = idxs[g * 16 + r16] - kg * 8;
        uint4v m;
#pragma unroll
        for (int q = 0; q < 4; ++q) {
            unsigned lo = (rel == 2 * q)     ? 0xFFFFu : 0u;
            unsigned hi = (rel == 2 * q + 1) ? 0xFFFFu : 0u;
            m[q] = lo | (hi << 16);
        }
        msk[g] = m;
    }

    // ---- A stream: lane reads W[h0+r16][ (j0+s)*32 + kg*8 .. +8 ] ----
    const float* ap = w + (size_t)(h0 + r16) * K + (size_t)j0 * I + kg * 8;

    f32x4 acc[8];
#pragma unroll
    for (int g = 0; g < 8; ++g) acc[g] = f32x4{0.f, 0.f, 0.f, 0.f};

    // depth-2 register pipeline, zero barriers
    float4 c0 = *reinterpret_cast<const float4*>(ap);
    float4 c1 = *reinterpret_cast<const float4*>(ap + 4);
    float4 n0 = *reinterpret_cast<const float4*>(ap + 32);
    float4 n1 = *reinterpret_cast<const float4*>(ap + 36);
    float4 t0 = c0, t1 = c1;

    for (int s = 0; s < JC; ++s) {
        if (s + 2 < JC) {
            const float* p = ap + (size_t)(s + 2) * 32;
            t0 = *reinterpret_cast<const float4*>(p);
            t1 = *reinterpret_cast<const float4*>(p + 4);
        }
        short8 af;
        af[0] = (short)f2bf(c0.x); af[1] = (short)f2bf(c0.y);
        af[2] = (short)f2bf(c0.z); af[3] = (short)f2bf(c0.w);
        af[4] = (short)f2bf(c1.x); af[5] = (short)f2bf(c1.y);
        af[6] = (short)f2bf(c1.z); af[7] = (short)f2bf(c1.w);
#pragma unroll
        for (int g = 0; g < 8; ++g) {
            unsigned hv = hxs[s * B + g * 16 + r16];
            unsigned hv32 = hv | (hv << 16);
            uint4v xd;
#pragma unroll
            for (int q = 0; q < 4; ++q) xd[q] = msk[g][q] & hv32;
            acc[g] = __builtin_amdgcn_mfma_f32_16x16x32_bf16(
                af, __builtin_bit_cast(short8, xd), acc[g], 0, 0, 0);
        }
        c0 = n0; c1 = n1; n0 = t0; n1 = t1;
    }

    // ---- epilogue: C layout col=lane&15 (b), row=kg*4+rr (h) ----
    if constexpr (USE_WS) {
        float* pp = out + (size_t)by * (B * H);   // 'out' = partial base
#pragma unroll
        for (int g = 0; g < 8; ++g) {
            int b = g * 16 + r16;
            float4 vv = {acc[g][0], acc[g][1], acc[g][2], acc[g][3]};
            *reinterpret_cast<float4*>(&pp[(size_t)b * H + h0 + kg * 4]) = vv;
        }
    } else {
#pragma unroll
        for (int g = 0; g < 8; ++g) {
            int b = g * 16 + r16;
#pragma unroll
            for (int rr = 0; rr < 4; ++rr)
                atomicAdd(&out[(size_t)b * H + h0 + kg * 4 + rr], acc[g][rr]);
        }
    }
}

extern "C" void kernel_launch(void* const* d_in, const int* in_sizes, int n_in,
                              void* d_out, int out_size, void* d_ws, size_t ws_size,
                              hipStream_t stream) {
    const float* inp    = (const float*)d_in[0];
    const float* state  = (const float*)d_in[1];  // [1,B,H]
    const float* weight = (const float*)d_in[2];  // [H,H,I]
    const float* bias   = (const float*)d_in[3];  // [H,I]
    float* out = (float*)d_out;

    float* partial = (float*)d_ws;
    const size_t need = (size_t)SPLIT * B * H * sizeof(float);

    if (ws_size >= need) {
        sru_gemm_kernel<true><<<dim3(H / (16 * WPB), SPLIT), 256, 0, stream>>>(
            inp, state, weight, partial);
        sru_reduce_kernel<<<2 * B, 128, 0, stream>>>(
            inp, state, bias, partial, out);
    } else {
        sru_init_kernel<<<(B * H) / 256, 256, 0, stream>>>(inp, state, bias, out);
        sru_gemm_kernel<false><<<dim3(H / (16 * WPB), SPLIT), 256, 0, stream>>>(
            inp, state, weight, out);
    }
}